// Round 1
// baseline (364.550 us; speedup 1.0000x reference)
//
#include <hip/hip_runtime.h>
#include <hip/hip_bf16.h>
#include <stdint.h>

// Problem: out[m][n] = sum_k x[m][k] * W[n][k] + bias[n]
//   W[n][k] = centroids[indices[n][k]]  (codebook decode)
// M = 4*2048 = 8192, N = 4096, K = 4096, codebook K=256 entries.
// Strategy: decode W to bf16 (ws), convert x to bf16 (ws), then m97-structure
// bf16 MFMA GEMM (128x128 tile, BK=32, global_load_lds width-16).

typedef unsigned short u16;
typedef __attribute__((ext_vector_type(8))) short short8;   // bf16x8 fragment (4 VGPR)
typedef __attribute__((ext_vector_type(8))) u16   u16x8;
typedef __attribute__((ext_vector_type(4))) float f32x4;
typedef __attribute__((ext_vector_type(4))) int   i32x4;

constexpr int Mdim = 8192;
constexpr int Ndim = 4096;
constexpr int Kdim = 4096;
constexpr int BM = 128, BN = 128, BK = 32;

// round-to-nearest-even fp32 -> bf16 bits
__device__ __forceinline__ u16 f2bf(float f) {
  union { float f; uint32_t u; } v; v.f = f;
  uint32_t u = v.u;
  return (u16)((u + 0x7fffu + ((u >> 16) & 1u)) >> 16);
}

// ---------------- decode: weight_bf16[n*K + k] = bf16(cent[idx[n*K + k]]) ----
__global__ void decode_weight_kernel(const int* __restrict__ idx,
                                     const float* __restrict__ cent,
                                     u16* __restrict__ wb) {
  __shared__ u16 lut[256];
  const int t = threadIdx.x;
  if (t < 256) lut[t] = f2bf(cent[t]);
  __syncthreads();
  const size_t base = ((size_t)blockIdx.x * 256 + t) * 8;
  i32x4 i0 = *(const i32x4*)(idx + base);
  i32x4 i1 = *(const i32x4*)(idx + base + 4);
  u16x8 r;
  r[0] = lut[i0[0] & 255]; r[1] = lut[i0[1] & 255];
  r[2] = lut[i0[2] & 255]; r[3] = lut[i0[3] & 255];
  r[4] = lut[i1[0] & 255]; r[5] = lut[i1[1] & 255];
  r[6] = lut[i1[2] & 255]; r[7] = lut[i1[3] & 255];
  *(u16x8*)(wb + base) = r;
}

// ---------------- convert: x fp32 -> bf16 -----------------------------------
__global__ void cvt_x_kernel(const float* __restrict__ x, u16* __restrict__ xb) {
  const size_t base = ((size_t)blockIdx.x * 256 + threadIdx.x) * 8;
  f32x4 a = *(const f32x4*)(x + base);
  f32x4 b = *(const f32x4*)(x + base + 4);
  u16x8 r;
  r[0] = f2bf(a[0]); r[1] = f2bf(a[1]); r[2] = f2bf(a[2]); r[3] = f2bf(a[3]);
  r[4] = f2bf(b[0]); r[5] = f2bf(b[1]); r[6] = f2bf(b[2]); r[7] = f2bf(b[3]);
  *(u16x8*)(xb + base) = r;
}

// ---------------- async 16B global -> LDS -----------------------------------
__device__ __forceinline__ void async16(const u16* g, u16* l) {
  __builtin_amdgcn_global_load_lds(
      (const __attribute__((address_space(1))) void*)g,
      (__attribute__((address_space(3))) void*)l,
      16, 0, 0);
}

// ---------------- bf16 GEMM: C[m][n] = sum_k A[m][k]*B[n][k] + bias[n] ------
// m97 structure: 128x128 tile, BK=32, 256 threads (4 waves, 2x2),
// each wave -> 64x64 output via 4x4 fragments of 16x16x32 MFMA.
__global__ void gemm_bf16_kernel(const u16* __restrict__ A,   // [Mdim][Kdim]
                                 const u16* __restrict__ B,   // [Ndim][Kdim]
                                 const float* __restrict__ bias,
                                 float* __restrict__ C) {
  __shared__ u16 As[BM * BK];   // 8 KiB
  __shared__ u16 Bs[BN * BK];   // 8 KiB

  const int t    = threadIdx.x;
  const int lane = t & 63;
  const int w    = t >> 6;       // wave id 0..3
  const int wr   = w >> 1;       // wave row (0..1)
  const int wc   = w & 1;        // wave col (0..1)

  const int m0 = blockIdx.y * BM;
  const int n0 = blockIdx.x * BN;

  f32x4 acc[4][4] = {};

  // Staging: tile is 128 rows x 32 cols bf16 = 8192 B = 512 chunks of 16 B.
  // Thread t handles chunks t and t+256. chunk c -> row c>>2, col (c&3)*8.
  // LDS dest for chunk c is byte offset c*16 = wave-uniform base + lane*16. OK.
  const int c0   = t;
  const int row0 = c0 >> 2;
  const int col0 = (c0 & 3) * 8;

  const u16* aSrc0 = A + (size_t)(m0 + row0) * Kdim + col0;
  const u16* aSrc1 = aSrc0 + (size_t)64 * Kdim;        // chunk c0+256 -> row+64
  const u16* bSrc0 = B + (size_t)(n0 + row0) * Kdim + col0;
  const u16* bSrc1 = bSrc0 + (size_t)64 * Kdim;

  u16* aDst0 = &As[(size_t)c0 * 8];
  u16* aDst1 = &As[(size_t)(c0 + 256) * 8];
  u16* bDst0 = &Bs[(size_t)c0 * 8];
  u16* bDst1 = &Bs[(size_t)(c0 + 256) * 8];

  const int fr = lane & 15;    // fragment row/col within 16
  const int fq = lane >> 4;    // 0..3: k-group for A/B, row-group for C/D

  for (int kt = 0; kt < Kdim / BK; ++kt) {
    __syncthreads();                      // previous compute done before overwrite
    const int ko = kt * BK;
    async16(aSrc0 + ko, aDst0);
    async16(aSrc1 + ko, aDst1);
    async16(bSrc0 + ko, bDst0);
    async16(bSrc1 + ko, bDst1);
    __syncthreads();                      // drains vmcnt + barrier

    short8 a[4], b[4];
#pragma unroll
    for (int mi = 0; mi < 4; ++mi)
      a[mi] = *(const short8*)&As[(wr * 64 + mi * 16 + fr) * BK + fq * 8];
#pragma unroll
    for (int ni = 0; ni < 4; ++ni)
      b[ni] = *(const short8*)&Bs[(wc * 64 + ni * 16 + fr) * BK + fq * 8];
#pragma unroll
    for (int mi = 0; mi < 4; ++mi)
#pragma unroll
      for (int ni = 0; ni < 4; ++ni)
        acc[mi][ni] = __builtin_amdgcn_mfma_f32_16x16x32_bf16(
            a[mi], b[ni], acc[mi][ni], 0, 0, 0);
  }

  // Epilogue: C/D layout col = lane&15, row = (lane>>4)*4 + reg  [verified m89]
  float bv[4];
#pragma unroll
  for (int ni = 0; ni < 4; ++ni)
    bv[ni] = bias[n0 + wc * 64 + ni * 16 + fr];

#pragma unroll
  for (int mi = 0; mi < 4; ++mi) {
#pragma unroll
    for (int j = 0; j < 4; ++j) {
      const int row = m0 + wr * 64 + mi * 16 + fq * 4 + j;
      float* cp = C + (size_t)row * Ndim + n0 + wc * 64 + fr;
#pragma unroll
      for (int ni = 0; ni < 4; ++ni)
        cp[ni * 16] = acc[mi][ni][j] + bv[ni];
    }
  }
}

extern "C" void kernel_launch(void* const* d_in, const int* in_sizes, int n_in,
                              void* d_out, int out_size, void* d_ws, size_t ws_size,
                              hipStream_t stream) {
  const float* x    = (const float*)d_in[0];   // [8192][4096] fp32
  const float* cent = (const float*)d_in[1];   // [256] fp32
  const float* bias = (const float*)d_in[2];   // [4096] fp32
  const int*   idx  = (const int*)d_in[3];     // [4096][4096] int
  float* out = (float*)d_out;                  // [8192][4096] fp32

  // workspace layout: [0, 32MiB) weight bf16; [32MiB, 96MiB) x bf16
  u16* wb = (u16*)d_ws;
  u16* xb = (u16*)((char*)d_ws + (size_t)Ndim * Kdim * sizeof(u16));

  decode_weight_kernel<<<(Ndim * Kdim) / (256 * 8), 256, 0, stream>>>(idx, cent, wb);
  cvt_x_kernel<<<((size_t)Mdim * Kdim) / (256 * 8), 256, 0, stream>>>(x, xb);

  dim3 grid(Ndim / BN, Mdim / BM);   // (32, 64)
  gemm_bf16_kernel<<<grid, 256, 0, stream>>>(xb, wb, bias, out);
}

// Round 2
// 306.240 us; speedup vs baseline: 1.1904x; 1.1904x over previous
//
#include <hip/hip_runtime.h>
#include <hip/hip_bf16.h>
#include <stdint.h>

// out[m][n] = sum_k x[m][k] * centroids[idx[n][k]] + bias[n]
// M=8192, N=4096, K=4096. decode W->bf16, cvt x->bf16, then 256x256 8-phase
// MFMA GEMM (T1 XCD swizzle + T2 LDS swizzle + T3/T4 counted vmcnt + T5 setprio).

typedef unsigned short u16;
typedef __attribute__((ext_vector_type(8))) short short8;   // bf16x8 (4 VGPR)
typedef __attribute__((ext_vector_type(8))) u16   u16x8;
typedef __attribute__((ext_vector_type(4))) float f32x4;
typedef __attribute__((ext_vector_type(4))) int   i32x4;

constexpr int Mdim = 8192;
constexpr int Ndim = 4096;
constexpr int Kdim = 4096;

__device__ __forceinline__ u16 f2bf(float f) {
  union { float f; uint32_t u; } v; v.f = f;
  uint32_t u = v.u;
  return (u16)((u + 0x7fffu + ((u >> 16) & 1u)) >> 16);
}

// ---------------- decode: weight_bf16[n*K + k] = bf16(cent[idx[n*K + k]]) ----
__global__ void decode_weight_kernel(const int* __restrict__ idx,
                                     const float* __restrict__ cent,
                                     u16* __restrict__ wb) {
  __shared__ u16 lut[256];
  const int t = threadIdx.x;
  if (t < 256) lut[t] = f2bf(cent[t]);
  __syncthreads();
  const size_t base = ((size_t)blockIdx.x * 256 + t) * 8;
  i32x4 i0 = *(const i32x4*)(idx + base);
  i32x4 i1 = *(const i32x4*)(idx + base + 4);
  u16x8 r;
  r[0] = lut[i0[0] & 255]; r[1] = lut[i0[1] & 255];
  r[2] = lut[i0[2] & 255]; r[3] = lut[i0[3] & 255];
  r[4] = lut[i1[0] & 255]; r[5] = lut[i1[1] & 255];
  r[6] = lut[i1[2] & 255]; r[7] = lut[i1[3] & 255];
  *(u16x8*)(wb + base) = r;
}

// ---------------- convert: x fp32 -> bf16 -----------------------------------
__global__ void cvt_x_kernel(const float* __restrict__ x, u16* __restrict__ xb) {
  const size_t base = ((size_t)blockIdx.x * 256 + threadIdx.x) * 8;
  f32x4 a = *(const f32x4*)(x + base);
  f32x4 b = *(const f32x4*)(x + base + 4);
  u16x8 r;
  r[0] = f2bf(a[0]); r[1] = f2bf(a[1]); r[2] = f2bf(a[2]); r[3] = f2bf(a[3]);
  r[4] = f2bf(b[0]); r[5] = f2bf(b[1]); r[6] = f2bf(b[2]); r[7] = f2bf(b[3]);
  *(u16x8*)(xb + base) = r;
}

// ---------------- async 16B global -> LDS -----------------------------------
__device__ __forceinline__ void async16(const u16* g, u16* l) {
  __builtin_amdgcn_global_load_lds(
      (const __attribute__((address_space(1))) void*)g,
      (__attribute__((address_space(3))) void*)l,
      16, 0, 0);
}

#define BAR() __builtin_amdgcn_s_barrier()
#define LGKM0() do { asm volatile("s_waitcnt lgkmcnt(0)" ::: "memory"); \
                     __builtin_amdgcn_sched_barrier(0); } while (0)
#define VMC4() asm volatile("s_waitcnt vmcnt(4)" ::: "memory")
#define VMC0() asm volatile("s_waitcnt vmcnt(0)" ::: "memory")

// ---------------- 256x256 8-phase bf16 GEMM ---------------------------------
// 512 threads = 8 waves (2 M-waves x 4 N-waves). BK=64, dbuf LDS 128 KiB.
// LDS layout per half (128 rows x 64 cols bf16): 16x32-elem subtiles, each
// 1 KiB contiguous; within a subtile, element col slot = col ^ ((r16&12)<<1)
// (bank-conflict swizzle, involution). global_load_lds writes LDS linearly;
// the SOURCE column is pre-swizzled so reads apply the same XOR.
__global__ __launch_bounds__(512, 2)
void gemm_bf16_kernel(const u16* __restrict__ A,   // [Mdim][Kdim] bf16
                      const u16* __restrict__ B,   // [Ndim][Kdim] bf16
                      const float* __restrict__ bias,
                      float* __restrict__ C) {
  __shared__ u16 AsF[32768];   // [buf][half][8192 elems] = 64 KiB
  __shared__ u16 BsF[32768];

  const int t    = threadIdx.x;
  const int lane = t & 63;
  const int w    = t >> 6;      // wave 0..7
  const int wm   = w >> 2;      // 0..1  -> A rows wm*128..+127
  const int wn   = w & 3;       // 0..3  -> B rows wn*64..+63
  const int fr   = lane & 15;
  const int fq   = lane >> 4;
  const int cswz = (fr & 12) << 1;

  // T1: XCD-aware block swizzle (512 blocks, 512%8==0 -> simple form OK)
  const int bid = blockIdx.x;
  const int swz = (bid & 7) * 64 + (bid >> 3);
  const int m0 = (swz >> 4) * 256;   // 32 M-tiles
  const int n0 = (swz & 15) * 256;   // 16 N-tiles

  // staging geometry: chunk c = l*512 + w*64 + lane (16 B each), LDS linear.
  const int c0   = w * 64 + lane;                    // chunk for l=0
  const int r16s = (c0 & 63) >> 2;
  const int srow = ((c0 >> 7) << 4) + r16s;          // 0..63 (l=1 -> +64)
  const int scol = ((c0 >> 6) & 1) * 32 + (((c0 & 3) * 8) ^ ((r16s & 12) << 1));
  const u16* pA = A + (size_t)(m0 + srow) * Kdim + scol;
  const u16* pB = B + (size_t)(n0 + srow) * Kdim + scol;
  const int dsto = c0 * 8;                           // LDS elem offset

  // fragment read offsets (elements): (rt*2+kk)*512 + fr*32 + swizzled col
  const int aoff = wm * 8192 + fr * 32 + ((fq * 8) ^ cswz);
  const int boff = (wn >> 1) * 8192 + (wn & 1) * 4096 + fr * 32 + ((fq * 8) ^ cswz);

  f32x4 acc[8][4] = {};
  short8 bf[2][4];   // [kk][ni], live across a K-tile
  short8 af[2][2];   // [kk][i],  per phase

  auto stageA = [&](int tk, int h) {
    const u16* s = pA + (size_t)h * (128 * Kdim) + tk * 64;
    u16* d = &AsF[((tk & 1) * 2 + h) * 8192 + dsto];
    async16(s, d);
    async16(s + (size_t)(64 * Kdim), d + 4096);
  };
  auto stageB = [&](int tk, int h) {
    const u16* s = pB + (size_t)h * (128 * Kdim) + tk * 64;
    u16* d = &BsF[((tk & 1) * 2 + h) * 8192 + dsto];
    async16(s, d);
    async16(s + (size_t)(64 * Kdim), d + 4096);
  };
  auto rdB = [&](int BUF) {
#pragma unroll
    for (int kk = 0; kk < 2; ++kk)
#pragma unroll
      for (int ni = 0; ni < 4; ++ni)
        bf[kk][ni] = *(const short8*)&BsF[BUF * 16384 + boff + (ni * 2 + kk) * 512];
  };
  auto rdA = [&](int BUF, int q) {
#pragma unroll
    for (int kk = 0; kk < 2; ++kk)
#pragma unroll
      for (int i = 0; i < 2; ++i)
        af[kk][i] = *(const short8*)&AsF[BUF * 16384 + aoff + ((q * 2 + i) * 2 + kk) * 512];
  };
  auto mfmaQ = [&](int q) {
    __builtin_amdgcn_s_setprio(1);
#pragma unroll
    for (int kk = 0; kk < 2; ++kk)
#pragma unroll
      for (int i = 0; i < 2; ++i)
#pragma unroll
        for (int ni = 0; ni < 4; ++ni)
          acc[q * 2 + i][ni] = __builtin_amdgcn_mfma_f32_16x16x32_bf16(
              af[kk][i], bf[kk][ni], acc[q * 2 + i][ni], 0, 0, 0);
    __builtin_amdgcn_s_setprio(0);
  };

  // One K-tile = 4 phases. Issue slots (steady state, all WAR/RAW safe):
  //   p0: A-half0(tk+1)   p1: A-half1(tk+1) + B-half0(tk+2)   p2: B-half1(tk+2)
  //   p3: after MFMA, vmcnt(4) -> all of K-tile tk+1 landed (in-order retire),
  //       only B halves of tk+2 stay in flight. Never drains to 0 mid-loop.
#define KT(TK, BUF, DOA, DOB, WAITK)                                    \
  {                                                                     \
    rdB(BUF); rdA(BUF, 0);                                              \
    if (DOA) stageA((TK) + 1, 0);                                       \
    BAR(); LGKM0(); mfmaQ(0); BAR();                                    \
    rdA(BUF, 1);                                                        \
    if (DOA) stageA((TK) + 1, 1);                                       \
    if (DOB) stageB((TK) + 2, 0);                                       \
    BAR(); LGKM0(); mfmaQ(1); BAR();                                    \
    rdA(BUF, 2);                                                        \
    if (DOB) stageB((TK) + 2, 1);                                       \
    BAR(); LGKM0(); mfmaQ(2); BAR();                                    \
    rdA(BUF, 3);                                                        \
    BAR(); LGKM0(); mfmaQ(3);                                           \
    if ((WAITK) == 0) { VMC4(); } else if ((WAITK) == 1) { VMC0(); }    \
    BAR();                                                              \
  }

  // Prologue: K-tile 0 fully + B halves of K-tile 1; wait first 8 loads.
  stageA(0, 0); stageA(0, 1); stageB(0, 0); stageB(0, 1);
  stageB(1, 0); stageB(1, 1);
  VMC4();
  BAR();

  for (int t2 = 0; t2 < 31; ++t2) {       // K-tiles 0..61
    const int k0 = 2 * t2;
    KT(k0,     0, 1, 1, 0);
    KT(k0 + 1, 1, 1, 1, 0);
  }
  KT(62, 0, 1, 0, 1);                     // stage A(63); drain to 0
  KT(63, 1, 0, 0, 2);                     // no staging, no wait

  // Epilogue: C/D map col=lane&15, row=(lane>>4)*4+j  [m89]
  float bv[4];
#pragma unroll
  for (int ni = 0; ni < 4; ++ni)
    bv[ni] = bias[n0 + wn * 64 + ni * 16 + fr];

#pragma unroll
  for (int mi = 0; mi < 8; ++mi) {
#pragma unroll
    for (int j = 0; j < 4; ++j) {
      const int row = m0 + wm * 128 + mi * 16 + fq * 4 + j;
      float* cp = C + (size_t)row * Ndim + n0 + wn * 64 + fr;
#pragma unroll
      for (int ni = 0; ni < 4; ++ni)
        cp[ni * 16] = acc[mi][ni][j] + bv[ni];
    }
  }
}

extern "C" void kernel_launch(void* const* d_in, const int* in_sizes, int n_in,
                              void* d_out, int out_size, void* d_ws, size_t ws_size,
                              hipStream_t stream) {
  const float* x    = (const float*)d_in[0];   // [8192][4096] fp32
  const float* cent = (const float*)d_in[1];   // [256] fp32
  const float* bias = (const float*)d_in[2];   // [4096] fp32
  const int*   idx  = (const int*)d_in[3];     // [4096][4096] int
  float* out = (float*)d_out;                  // [8192][4096] fp32

  u16* wb = (u16*)d_ws;
  u16* xb = (u16*)((char*)d_ws + (size_t)Ndim * Kdim * sizeof(u16));

  decode_weight_kernel<<<(Ndim * Kdim) / (256 * 8), 256, 0, stream>>>(idx, cent, wb);
  cvt_x_kernel<<<((size_t)Mdim * Kdim) / (256 * 8), 256, 0, stream>>>(x, xb);

  gemm_bf16_kernel<<<dim3(512), 512, 0, stream>>>(xb, wb, bias, out);
}

// Round 3
// 288.572 us; speedup vs baseline: 1.2633x; 1.0612x over previous
//
#include <hip/hip_runtime.h>
#include <hip/hip_bf16.h>
#include <stdint.h>

// out[m][n] = sum_k x[m][k] * centroids[idx[n][k]] + bias[n]
// M=8192, N=4096, K=4096. decode W->bf16, cvt x->bf16, then 256x256 8-phase
// MFMA GEMM (T1 XCD swizzle + T2 LDS swizzle + T3/T4 counted vmcnt + T5 setprio).
// Round 3: swizzle fixed to g(fr)=(fr>>1)&3 (fr bits 1-2), so every 8
// consecutive lanes of a ds_read_b128 cover all 8 16B-slots (conflict-free
// under both in-order and balanced LDS scheduling models).

typedef unsigned short u16;
typedef __attribute__((ext_vector_type(8))) short short8;   // bf16x8 (4 VGPR)
typedef __attribute__((ext_vector_type(8))) u16   u16x8;
typedef __attribute__((ext_vector_type(4))) float f32x4;
typedef __attribute__((ext_vector_type(4))) int   i32x4;

constexpr int Mdim = 8192;
constexpr int Ndim = 4096;
constexpr int Kdim = 4096;

__device__ __forceinline__ u16 f2bf(float f) {
  union { float f; uint32_t u; } v; v.f = f;
  uint32_t u = v.u;
  return (u16)((u + 0x7fffu + ((u >> 16) & 1u)) >> 16);
}

// ---------------- decode: weight_bf16[n*K + k] = bf16(cent[idx[n*K + k]]) ----
__global__ void decode_weight_kernel(const int* __restrict__ idx,
                                     const float* __restrict__ cent,
                                     u16* __restrict__ wb) {
  __shared__ u16 lut[256];
  const int t = threadIdx.x;
  if (t < 256) lut[t] = f2bf(cent[t]);
  __syncthreads();
  const size_t base = ((size_t)blockIdx.x * 256 + t) * 8;
  i32x4 i0 = *(const i32x4*)(idx + base);
  i32x4 i1 = *(const i32x4*)(idx + base + 4);
  u16x8 r;
  r[0] = lut[i0[0] & 255]; r[1] = lut[i0[1] & 255];
  r[2] = lut[i0[2] & 255]; r[3] = lut[i0[3] & 255];
  r[4] = lut[i1[0] & 255]; r[5] = lut[i1[1] & 255];
  r[6] = lut[i1[2] & 255]; r[7] = lut[i1[3] & 255];
  *(u16x8*)(wb + base) = r;
}

// ---------------- convert: x fp32 -> bf16 -----------------------------------
__global__ void cvt_x_kernel(const float* __restrict__ x, u16* __restrict__ xb) {
  const size_t base = ((size_t)blockIdx.x * 256 + threadIdx.x) * 8;
  f32x4 a = *(const f32x4*)(x + base);
  f32x4 b = *(const f32x4*)(x + base + 4);
  u16x8 r;
  r[0] = f2bf(a[0]); r[1] = f2bf(a[1]); r[2] = f2bf(a[2]); r[3] = f2bf(a[3]);
  r[4] = f2bf(b[0]); r[5] = f2bf(b[1]); r[6] = f2bf(b[2]); r[7] = f2bf(b[3]);
  *(u16x8*)(xb + base) = r;
}

// ---------------- async 16B global -> LDS -----------------------------------
__device__ __forceinline__ void async16(const u16* g, u16* l) {
  __builtin_amdgcn_global_load_lds(
      (const __attribute__((address_space(1))) void*)g,
      (__attribute__((address_space(3))) void*)l,
      16, 0, 0);
}

#define BAR() __builtin_amdgcn_s_barrier()
#define LGKM0() do { asm volatile("s_waitcnt lgkmcnt(0)" ::: "memory"); \
                     __builtin_amdgcn_sched_barrier(0); } while (0)
#define VMC4() asm volatile("s_waitcnt vmcnt(4)" ::: "memory")
#define VMC0() asm volatile("s_waitcnt vmcnt(0)" ::: "memory")

// ---------------- 256x256 8-phase bf16 GEMM ---------------------------------
// 512 threads = 8 waves (2 M-waves x 4 N-waves). BK=64, dbuf LDS 128 KiB.
// LDS layout per half (128 rows x 64 cols bf16): 16x32-elem subtiles, each
// 1 KiB contiguous; within a subtile, quad slot = (col>>3) ^ ((r16>>1)&3).
// global_load_lds writes LDS linearly; the SOURCE column is pre-swizzled so
// reads apply the same XOR.
__global__ __launch_bounds__(512, 2)
void gemm_bf16_kernel(const u16* __restrict__ A,   // [Mdim][Kdim] bf16
                      const u16* __restrict__ B,   // [Ndim][Kdim] bf16
                      const float* __restrict__ bias,
                      float* __restrict__ C) {
  __shared__ u16 AsF[32768];   // [buf][half][8192 elems] = 64 KiB
  __shared__ u16 BsF[32768];

  const int t    = threadIdx.x;
  const int lane = t & 63;
  const int w    = t >> 6;      // wave 0..7
  const int wm   = w >> 2;      // 0..1  -> A rows wm*128..+127
  const int wn   = w & 3;       // 0..3  -> B rows wn*64..+63
  const int fr   = lane & 15;
  const int fq   = lane >> 4;
  const int cswz = (fr & 6) << 2;   // g(fr)*8 = ((fr>>1)&3)*8

  // T1: XCD-aware block swizzle (512 blocks, 512%8==0 -> simple form OK)
  const int bid = blockIdx.x;
  const int swz = (bid & 7) * 64 + (bid >> 3);
  const int m0 = (swz >> 4) * 256;   // 32 M-tiles
  const int n0 = (swz & 15) * 256;   // 16 N-tiles

  // staging geometry: chunk c = l*512 + w*64 + lane (16 B each), LDS linear.
  const int c0   = w * 64 + lane;                    // chunk for l=0
  const int r16s = (c0 & 63) >> 2;
  const int srow = ((c0 >> 7) << 4) + r16s;          // 0..63 (l=1 -> +64)
  const int scol = ((c0 >> 6) & 1) * 32 + (((c0 & 3) * 8) ^ ((r16s & 6) << 2));
  const u16* pA = A + (size_t)(m0 + srow) * Kdim + scol;
  const u16* pB = B + (size_t)(n0 + srow) * Kdim + scol;
  const int dsto = c0 * 8;                           // LDS elem offset

  // fragment read offsets (elements): (rt*2+kk)*512 + fr*32 + swizzled col
  const int aoff = wm * 8192 + fr * 32 + ((fq * 8) ^ cswz);
  const int boff = (wn >> 1) * 8192 + (wn & 1) * 4096 + fr * 32 + ((fq * 8) ^ cswz);

  f32x4 acc[8][4] = {};
  short8 bf[2][4];   // [kk][ni], live across a K-tile
  short8 af[2][2];   // [kk][i],  per phase

  auto stageA = [&](int tk, int h) {
    const u16* s = pA + (size_t)h * (128 * Kdim) + tk * 64;
    u16* d = &AsF[((tk & 1) * 2 + h) * 8192 + dsto];
    async16(s, d);
    async16(s + (size_t)(64 * Kdim), d + 4096);
  };
  auto stageB = [&](int tk, int h) {
    const u16* s = pB + (size_t)h * (128 * Kdim) + tk * 64;
    u16* d = &BsF[((tk & 1) * 2 + h) * 8192 + dsto];
    async16(s, d);
    async16(s + (size_t)(64 * Kdim), d + 4096);
  };
  auto rdB = [&](int BUF) {
#pragma unroll
    for (int kk = 0; kk < 2; ++kk)
#pragma unroll
      for (int ni = 0; ni < 4; ++ni)
        bf[kk][ni] = *(const short8*)&BsF[BUF * 16384 + boff + (ni * 2 + kk) * 512];
  };
  auto rdA = [&](int BUF, int q) {
#pragma unroll
    for (int kk = 0; kk < 2; ++kk)
#pragma unroll
      for (int i = 0; i < 2; ++i)
        af[kk][i] = *(const short8*)&AsF[BUF * 16384 + aoff + ((q * 2 + i) * 2 + kk) * 512];
  };
  auto mfmaQ = [&](int q) {
    __builtin_amdgcn_s_setprio(1);
#pragma unroll
    for (int kk = 0; kk < 2; ++kk)
#pragma unroll
      for (int i = 0; i < 2; ++i)
#pragma unroll
        for (int ni = 0; ni < 4; ++ni)
          acc[q * 2 + i][ni] = __builtin_amdgcn_mfma_f32_16x16x32_bf16(
              af[kk][i], bf[kk][ni], acc[q * 2 + i][ni], 0, 0, 0);
    __builtin_amdgcn_s_setprio(0);
  };

  // One K-tile = 4 phases. Issue slots (steady state, all WAR/RAW safe):
  //   p0: A-half0(tk+1)   p1: A-half1(tk+1) + B-half0(tk+2)   p2: B-half1(tk+2)
  //   p3: after MFMA, vmcnt(4) -> all of K-tile tk+1 landed (in-order retire),
  //       only B halves of tk+2 stay in flight. Never drains to 0 mid-loop.
#define KT(TK, BUF, DOA, DOB, WAITK)                                    \
  {                                                                     \
    rdB(BUF); rdA(BUF, 0);                                              \
    if (DOA) stageA((TK) + 1, 0);                                       \
    BAR(); LGKM0(); mfmaQ(0); BAR();                                    \
    rdA(BUF, 1);                                                        \
    if (DOA) stageA((TK) + 1, 1);                                       \
    if (DOB) stageB((TK) + 2, 0);                                       \
    BAR(); LGKM0(); mfmaQ(1); BAR();                                    \
    rdA(BUF, 2);                                                        \
    if (DOB) stageB((TK) + 2, 1);                                       \
    BAR(); LGKM0(); mfmaQ(2); BAR();                                    \
    rdA(BUF, 3);                                                        \
    BAR(); LGKM0(); mfmaQ(3);                                           \
    if ((WAITK) == 0) { VMC4(); } else if ((WAITK) == 1) { VMC0(); }    \
    BAR();                                                              \
  }

  // Prologue: K-tile 0 fully + B halves of K-tile 1; wait first 8 loads.
  stageA(0, 0); stageA(0, 1); stageB(0, 0); stageB(0, 1);
  stageB(1, 0); stageB(1, 1);
  VMC4();
  BAR();

  for (int t2 = 0; t2 < 31; ++t2) {       // K-tiles 0..61
    const int k0 = 2 * t2;
    KT(k0,     0, 1, 1, 0);
    KT(k0 + 1, 1, 1, 1, 0);
  }
  KT(62, 0, 1, 0, 1);                     // stage A(63); drain to 0
  KT(63, 1, 0, 0, 2);                     // no staging, no wait

  // Epilogue: C/D map col=lane&15, row=(lane>>4)*4+j  [m89]
  float bv[4];
#pragma unroll
  for (int ni = 0; ni < 4; ++ni)
    bv[ni] = bias[n0 + wn * 64 + ni * 16 + fr];

#pragma unroll
  for (int mi = 0; mi < 8; ++mi) {
#pragma unroll
    for (int j = 0; j < 4; ++j) {
      const int row = m0 + wm * 128 + mi * 16 + fq * 4 + j;
      float* cp = C + (size_t)row * Ndim + n0 + wn * 64 + fr;
#pragma unroll
      for (int ni = 0; ni < 4; ++ni)
        cp[ni * 16] = acc[mi][ni][j] + bv[ni];
    }
  }
}

extern "C" void kernel_launch(void* const* d_in, const int* in_sizes, int n_in,
                              void* d_out, int out_size, void* d_ws, size_t ws_size,
                              hipStream_t stream) {
  const float* x    = (const float*)d_in[0];   // [8192][4096] fp32
  const float* cent = (const float*)d_in[1];   // [256] fp32
  const float* bias = (const float*)d_in[2];   // [4096] fp32
  const int*   idx  = (const int*)d_in[3];     // [4096][4096] int
  float* out = (float*)d_out;                  // [8192][4096] fp32

  u16* wb = (u16*)d_ws;
  u16* xb = (u16*)((char*)d_ws + (size_t)Ndim * Kdim * sizeof(u16));

  decode_weight_kernel<<<(Ndim * Kdim) / (256 * 8), 256, 0, stream>>>(idx, cent, wb);
  cvt_x_kernel<<<((size_t)Mdim * Kdim) / (256 * 8), 256, 0, stream>>>(x, xb);

  gemm_bf16_kernel<<<dim3(512), 512, 0, stream>>>(xb, wb, bias, out);
}

// Round 4
// 285.035 us; speedup vs baseline: 1.2790x; 1.0124x over previous
//
#include <hip/hip_runtime.h>
#include <hip/hip_bf16.h>
#include <stdint.h>

// out[m][n] = sum_k x[m][k] * centroids[idx[n][k]] + bias[n]
// M=8192, N=4096, K=4096. decode W->bf16, cvt x->bf16, then 256x256 8-phase
// MFMA GEMM. Round 4: software-pipelined ds_reads (one phase ahead, counted
// lgkmcnt(4)); K-tile-boundary reads interleaved inside q3's MFMA cluster.

typedef unsigned short u16;
typedef __attribute__((ext_vector_type(8))) short short8;   // bf16x8 (4 VGPR)
typedef __attribute__((ext_vector_type(8))) u16   u16x8;
typedef __attribute__((ext_vector_type(4))) float f32x4;
typedef __attribute__((ext_vector_type(4))) int   i32x4;

constexpr int Mdim = 8192;
constexpr int Ndim = 4096;
constexpr int Kdim = 4096;

__device__ __forceinline__ u16 f2bf(float f) {
  union { float f; uint32_t u; } v; v.f = f;
  uint32_t u = v.u;
  return (u16)((u + 0x7fffu + ((u >> 16) & 1u)) >> 16);
}

// ---------------- decode: weight_bf16[n*K + k] = bf16(cent[idx[n*K + k]]) ----
__global__ void decode_weight_kernel(const int* __restrict__ idx,
                                     const float* __restrict__ cent,
                                     u16* __restrict__ wb) {
  __shared__ u16 lut[256];
  const int t = threadIdx.x;
  if (t < 256) lut[t] = f2bf(cent[t]);
  __syncthreads();
  const size_t base = ((size_t)blockIdx.x * 256 + t) * 8;
  i32x4 i0 = *(const i32x4*)(idx + base);
  i32x4 i1 = *(const i32x4*)(idx + base + 4);
  u16x8 r;
  r[0] = lut[i0[0] & 255]; r[1] = lut[i0[1] & 255];
  r[2] = lut[i0[2] & 255]; r[3] = lut[i0[3] & 255];
  r[4] = lut[i1[0] & 255]; r[5] = lut[i1[1] & 255];
  r[6] = lut[i1[2] & 255]; r[7] = lut[i1[3] & 255];
  *(u16x8*)(wb + base) = r;
}

// ---------------- convert: x fp32 -> bf16 -----------------------------------
__global__ void cvt_x_kernel(const float* __restrict__ x, u16* __restrict__ xb) {
  const size_t base = ((size_t)blockIdx.x * 256 + threadIdx.x) * 8;
  f32x4 a = *(const f32x4*)(x + base);
  f32x4 b = *(const f32x4*)(x + base + 4);
  u16x8 r;
  r[0] = f2bf(a[0]); r[1] = f2bf(a[1]); r[2] = f2bf(a[2]); r[3] = f2bf(a[3]);
  r[4] = f2bf(b[0]); r[5] = f2bf(b[1]); r[6] = f2bf(b[2]); r[7] = f2bf(b[3]);
  *(u16x8*)(xb + base) = r;
}

// ---------------- async 16B global -> LDS -----------------------------------
__device__ __forceinline__ void async16(const u16* g, u16* l) {
  __builtin_amdgcn_global_load_lds(
      (const __attribute__((address_space(1))) void*)g,
      (__attribute__((address_space(3))) void*)l,
      16, 0, 0);
}

#define BAR()   __builtin_amdgcn_s_barrier()
#define LGKM0() asm volatile("s_waitcnt lgkmcnt(0)" ::: "memory")
#define LGKM4() asm volatile("s_waitcnt lgkmcnt(4)" ::: "memory")
#define VMC4()  asm volatile("s_waitcnt vmcnt(4)" ::: "memory")
#define VMC0()  asm volatile("s_waitcnt vmcnt(0)" ::: "memory")

// ---------------- 256x256 8-phase bf16 GEMM ---------------------------------
// 512 threads = 8 waves (2 M-waves x 4 N-waves). BK=64, dbuf LDS 128 KiB.
// LDS per half: 16x32-elem subtiles (1 KiB); quad slot = (col>>3) ^ ((r>>1)&3).
// Pipelined reads: phase p issues reads for phase p+1; counted lgkmcnt(4)
// waits only the previous phase's reads. Boundary (q0+B) reads for tile T+1
// are issued inside tile T's q3 MFMA cluster (after vmcnt(4)+BAR).
__global__ __launch_bounds__(512, 2)
void gemm_bf16_kernel(const u16* __restrict__ A,   // [Mdim][Kdim] bf16
                      const u16* __restrict__ B,   // [Ndim][Kdim] bf16
                      const float* __restrict__ bias,
                      float* __restrict__ C) {
  __shared__ u16 AsF[32768];   // [buf][half][8192 elems] = 64 KiB
  __shared__ u16 BsF[32768];

  const int t    = threadIdx.x;
  const int lane = t & 63;
  const int w    = t >> 6;      // wave 0..7
  const int wm   = w >> 2;      // 0..1  -> A rows wm*128..+127
  const int wn   = w & 3;       // 0..3  -> B rows wn*64..+63
  const int fr   = lane & 15;
  const int fq   = lane >> 4;
  const int cswz = (fr & 6) << 2;   // g(fr)*8 = ((fr>>1)&3)*8

  // T1: XCD-aware block swizzle (512 blocks, 512%8==0 -> simple form OK)
  const int bid = blockIdx.x;
  const int swz = (bid & 7) * 64 + (bid >> 3);
  const int m0 = (swz >> 4) * 256;   // 32 M-tiles
  const int n0 = (swz & 15) * 256;   // 16 N-tiles

  // staging geometry: chunk c = l*512 + w*64 + lane (16 B each), LDS linear.
  const int c0   = w * 64 + lane;                    // chunk for l=0
  const int r16s = (c0 & 63) >> 2;
  const int srow = ((c0 >> 7) << 4) + r16s;          // 0..63 (l=1 -> +64)
  const int scol = ((c0 >> 6) & 1) * 32 + (((c0 & 3) * 8) ^ ((r16s & 6) << 2));
  const u16* pA = A + (size_t)(m0 + srow) * Kdim + scol;
  const u16* pB = B + (size_t)(n0 + srow) * Kdim + scol;
  const int dsto = c0 * 8;                           // LDS elem offset

  // fragment read offsets (elements): (rt*2+kk)*512 + fr*32 + swizzled col
  const int aoff = wm * 8192 + fr * 32 + ((fq * 8) ^ cswz);
  const int boff = (wn >> 1) * 8192 + (wn & 1) * 4096 + fr * 32 + ((fq * 8) ^ cswz);

  f32x4 acc[8][4] = {};
  short8 bf[2][4];      // [kk][ni], refreshed in-place at tile boundary
  short8 afA[2][2];     // even-q A frags (q0, q2)
  short8 afB[2][2];     // odd-q  A frags (q1, q3)

  auto stageA = [&](int tk, int h) {
    const u16* s = pA + (size_t)h * (128 * Kdim) + tk * 64;
    u16* d = &AsF[((tk & 1) * 2 + h) * 8192 + dsto];
    async16(s, d);
    async16(s + (size_t)(64 * Kdim), d + 4096);
  };
  auto stageB = [&](int tk, int h) {
    const u16* s = pB + (size_t)h * (128 * Kdim) + tk * 64;
    u16* d = &BsF[((tk & 1) * 2 + h) * 8192 + dsto];
    async16(s, d);
    async16(s + (size_t)(64 * Kdim), d + 4096);
  };
  auto rdB_kk = [&](int BUF, int kk) {
#pragma unroll
    for (int ni = 0; ni < 4; ++ni)
      bf[kk][ni] = *(const short8*)&BsF[BUF * 16384 + boff + (ni * 2 + kk) * 512];
  };
  auto rdA_A = [&](int BUF, int q) {
#pragma unroll
    for (int kk = 0; kk < 2; ++kk)
#pragma unroll
      for (int i = 0; i < 2; ++i)
        afA[kk][i] = *(const short8*)&AsF[BUF * 16384 + aoff + ((q * 2 + i) * 2 + kk) * 512];
  };
  auto rdA_B = [&](int BUF, int q) {
#pragma unroll
    for (int kk = 0; kk < 2; ++kk)
#pragma unroll
      for (int i = 0; i < 2; ++i)
        afB[kk][i] = *(const short8*)&AsF[BUF * 16384 + aoff + ((q * 2 + i) * 2 + kk) * 512];
  };
  auto mfmaE = [&](int q) {   // uses afA
    __builtin_amdgcn_s_setprio(1);
#pragma unroll
    for (int kk = 0; kk < 2; ++kk)
#pragma unroll
      for (int i = 0; i < 2; ++i)
#pragma unroll
        for (int ni = 0; ni < 4; ++ni)
          acc[q * 2 + i][ni] = __builtin_amdgcn_mfma_f32_16x16x32_bf16(
              afA[kk][i], bf[kk][ni], acc[q * 2 + i][ni], 0, 0, 0);
    __builtin_amdgcn_s_setprio(0);
  };
  auto mfmaO = [&](int q) {   // uses afB
    __builtin_amdgcn_s_setprio(1);
#pragma unroll
    for (int kk = 0; kk < 2; ++kk)
#pragma unroll
      for (int i = 0; i < 2; ++i)
#pragma unroll
        for (int ni = 0; ni < 4; ++ni)
          acc[q * 2 + i][ni] = __builtin_amdgcn_mfma_f32_16x16x32_bf16(
              afB[kk][i], bf[kk][ni], acc[q * 2 + i][ni], 0, 0, 0);
    __builtin_amdgcn_s_setprio(0);
  };
  auto mfmaO_kk = [&](int q, int kk) {   // one kk-half of an odd q
    __builtin_amdgcn_s_setprio(1);
#pragma unroll
    for (int i = 0; i < 2; ++i)
#pragma unroll
      for (int ni = 0; ni < 4; ++ni)
        acc[q * 2 + i][ni] = __builtin_amdgcn_mfma_f32_16x16x32_bf16(
            afB[kk][i], bf[kk][ni], acc[q * 2 + i][ni], 0, 0, 0);
    __builtin_amdgcn_s_setprio(0);
  };

  // Tile T (BUF=T&1). Entry invariant: afA=q0 frags, bf=B(T) in flight (12
  // boundary ds_reads outstanding); vmem outstanding = 4 = B(T+1).
  // MODE: 0 normal (vmcnt(4) at p3), 1 pre-last (vmcnt(0)), 2 last (no
  // boundary reads, no vmcnt).
#define KT(TK, BUF, DOA, DOB, MODE)                                     \
  {                                                                     \
    /* p0 */                                                            \
    rdA_B((BUF), 1);                                                    \
    if (DOA) stageA((TK) + 1, 0);                                       \
    BAR(); LGKM4();          /* boundary 12 done; rdA(q1) in flight */  \
    mfmaE(0);                                                           \
    BAR();                                                              \
    /* p1 */                                                            \
    rdA_A((BUF), 2);                                                    \
    if (DOA) stageA((TK) + 1, 1);                                       \
    if (DOB) stageB((TK) + 2, 0);                                       \
    BAR(); LGKM4();          /* rdA(q1) done */                         \
    mfmaO(1);                                                           \
    BAR();                                                              \
    /* p2 */                                                            \
    rdA_B((BUF), 3);                                                    \
    if (DOB) stageB((TK) + 2, 1);                                       \
    BAR(); LGKM4();          /* rdA(q2) done */                         \
    mfmaE(2);                                                           \
    BAR();                                                              \
    /* p3: boundary */                                                  \
    if ((MODE) == 0) { VMC4(); } else if ((MODE) == 1) { VMC0(); }      \
    BAR();                   /* all waves' A(T+1)/B(T+1) landed */      \
    LGKM0();                 /* rdA(q3) done */                         \
    mfmaO_kk(3, 0);                                                     \
    if ((MODE) < 2) rdB_kk((BUF) ^ 1, 0);                               \
    mfmaO_kk(3, 1);                                                     \
    if ((MODE) < 2) { rdB_kk((BUF) ^ 1, 1); rdA_A((BUF) ^ 1, 0); }      \
    BAR();                                                              \
  }

  // Prologue: stage A(0),B(0),B(1); wait first 8 (leave B(1)=4 in flight);
  // then issue tile-0 boundary reads.
  stageA(0, 0); stageA(0, 1); stageB(0, 0); stageB(0, 1);
  stageB(1, 0); stageB(1, 1);
  VMC4();
  BAR();
  rdB_kk(0, 0); rdB_kk(0, 1); rdA_A(0, 0);

  for (int t2 = 0; t2 < 31; ++t2) {       // K-tiles 0..61
    const int k0 = 2 * t2;
    KT(k0,     0, 1, 1, 0);
    KT(k0 + 1, 1, 1, 1, 0);
  }
  KT(62, 0, 1, 0, 1);                     // stage A(63); drain vmcnt to 0
  KT(63, 1, 0, 0, 2);                     // last: no staging, no boundary

  // Epilogue: C/D map col=lane&15, row=(lane>>4)*4+j  [m89]
  float bv[4];
#pragma unroll
  for (int ni = 0; ni < 4; ++ni)
    bv[ni] = bias[n0 + wn * 64 + ni * 16 + fr];

#pragma unroll
  for (int mi = 0; mi < 8; ++mi) {
#pragma unroll
    for (int j = 0; j < 4; ++j) {
      const int row = m0 + wm * 128 + mi * 16 + fq * 4 + j;
      float* cp = C + (size_t)row * Ndim + n0 + wn * 64 + fr;
#pragma unroll
      for (int ni = 0; ni < 4; ++ni)
        cp[ni * 16] = acc[mi][ni][j] + bv[ni];
    }
  }
#undef KT
}

extern "C" void kernel_launch(void* const* d_in, const int* in_sizes, int n_in,
                              void* d_out, int out_size, void* d_ws, size_t ws_size,
                              hipStream_t stream) {
  const float* x    = (const float*)d_in[0];   // [8192][4096] fp32
  const float* cent = (const float*)d_in[1];   // [256] fp32
  const float* bias = (const float*)d_in[2];   // [4096] fp32
  const int*   idx  = (const int*)d_in[3];     // [4096][4096] int
  float* out = (float*)d_out;                  // [8192][4096] fp32

  u16* wb = (u16*)d_ws;
  u16* xb = (u16*)((char*)d_ws + (size_t)Ndim * Kdim * sizeof(u16));

  decode_weight_kernel<<<(Ndim * Kdim) / (256 * 8), 256, 0, stream>>>(idx, cent, wb);
  cvt_x_kernel<<<((size_t)Mdim * Kdim) / (256 * 8), 256, 0, stream>>>(x, xb);

  gemm_bf16_kernel<<<dim3(512), 512, 0, stream>>>(xb, wb, bias, out);
}